// Round 6
// baseline (1507.460 us; speedup 1.0000x reference)
//
#include <hip/hip_runtime.h>
#include <hip/hip_fp16.h>

#define B_ 16
#define T_ 256
#define D_ 128
#define H_ 256
#define HP 264   // LDS h row pitch in halves (528 B: odd 16B multiple -> even bank spread)

typedef _Float16 f16;
typedef __attribute__((ext_vector_type(8))) _Float16 f16x8;
typedef __attribute__((ext_vector_type(4))) _Float16 f16x4;
typedef __attribute__((ext_vector_type(4))) float f32x4;

__device__ __forceinline__ float fast_rcp(float x) {
#if __has_builtin(__builtin_amdgcn_rcpf)
    return __builtin_amdgcn_rcpf(x);
#else
    return 1.0f / x;
#endif
}
__device__ __forceinline__ float sigmoid_f(float x) {
    return fast_rcp(1.0f + __expf(-x));
}
__device__ __forceinline__ float tanh_f(float x) {
    float e = __expf(2.0f * x);
    return 1.0f - 2.0f * fast_rcp(1.0f + e);
}

// ---- weight prep: Whh f32 [768][256] -> MFMA B-fragment order f16 ----
// layout idx = (((wv*2+u)*3+g)*8+kc)*64 + lane ; each cell = f16x8 of
// Whh[col = g*256 + wv*32 + u*16 + (lane&15)][k = kc*32 + (lane>>4)*8 .. +8]
__global__ void k_wprep(const float* __restrict__ wa, const float* __restrict__ wb,
                        f16x8* __restrict__ oa, f16x8* __restrict__ ob) {
    int idx = blockIdx.x * 256 + threadIdx.x;   // [0, 98304) : 2 mats x 49152
    const float* src = (idx < 49152) ? wa : wb;
    f16x8* dst = (idx < 49152) ? oa : ob;
    int i = idx & 49151;
    int l = i & 63;
    int kc = (i >> 6) & 7;
    int rest = i >> 9;        // (wv*2+u)*3+g
    int g = rest % 3;
    int uu = rest / 3;        // wv*2+u in [0,16)
    int col = g * 256 + (uu >> 1) * 32 + (uu & 1) * 16 + (l & 15);
    int k0 = kc * 32 + (l >> 4) * 8;
    const float* s = src + col * 256 + k0;
    f16x8 v;
#pragma unroll
    for (int q = 0; q < 8; ++q) v[q] = (f16)s[q];
    dst[i] = v;
}

// ---- mask precompute: pos[b][s] = first t with targets[b,t]==s (else T) ----
__global__ void k_pos_init(int* __restrict__ pos) {
    pos[blockIdx.x * 256 + threadIdx.x] = T_;
}
__global__ void k_pos_scan(const int* __restrict__ tgt, int* __restrict__ pos) {
    int i = blockIdx.x * 256 + threadIdx.x;
    int b = i >> 8, t = i & 255;
    int s = tgt[i] & 255;
    atomicMin(&pos[(b << 8) + s], t);
}

// ---- enc_in = inputs @ W_enc^T + b_enc ----
__global__ __launch_bounds__(256) void k_encA(const float* __restrict__ in,
                                              const float* __restrict__ W,
                                              const float* __restrict__ bias,
                                              float* __restrict__ out) {
    int bt0 = blockIdx.x * 8;
    int a = threadIdx.x;
    float bv = bias[a];
    float acc[8];
#pragma unroll
    for (int tt = 0; tt < 8; ++tt) acc[tt] = bv;
    const float* wr = W + a * D_;
    for (int k = 0; k < D_; k += 4) {
        float4 w4 = *(const float4*)(wr + k);
#pragma unroll
        for (int tt = 0; tt < 8; ++tt) {
            float4 x4 = *(const float4*)(in + (bt0 + tt) * D_ + k);
            acc[tt] += w4.x * x4.x + w4.y * x4.y + w4.z * x4.z + w4.w * x4.w;
        }
    }
#pragma unroll
    for (int tt = 0; tt < 8; ++tt) out[(bt0 + tt) * H_ + a] = acc[tt];
}

// ---- x_proj -> f16 fragment layout, bhh folded into r,z gates ----
__global__ __launch_bounds__(256) void k_proj3(const float* __restrict__ in,
                                               const float* __restrict__ W,
                                               const float* __restrict__ bih,
                                               const float* __restrict__ bhh,
                                               const int* __restrict__ tgt,
                                               f16* __restrict__ gout) {
    int bt0 = blockIdx.x * 8;
    int b = bt0 >> 8;
    int a = threadIdx.x;
    const float* rp[8];
#pragma unroll
    for (int tt = 0; tt < 8; ++tt) {
        int t = (bt0 & 255) + tt;
        int tsrc = t;
        if (tgt) tsrc = tgt[(b << 8) + ((t + 255) & 255)] & 255; // roll(targets,1)
        rp[tt] = in + ((b << 8) + tsrc) * H_;
    }
    float acc0[8], acc1[8], acc2[8];
    float b0 = bih[a] + bhh[a];               // r gate: fold bhh
    float b1 = bih[a + 256] + bhh[a + 256];   // z gate: fold bhh
    float b2 = bih[a + 512];                  // n gate: bhh applied inside GRU
#pragma unroll
    for (int tt = 0; tt < 8; ++tt) { acc0[tt] = b0; acc1[tt] = b1; acc2[tt] = b2; }
    const float* w0 = W + a * H_;
    const float* w1 = W + (a + 256) * H_;
    const float* w2 = W + (a + 512) * H_;
    for (int k = 0; k < H_; k += 4) {
        float4 a4 = *(const float4*)(w0 + k);
        float4 b4 = *(const float4*)(w1 + k);
        float4 c4 = *(const float4*)(w2 + k);
#pragma unroll
        for (int tt = 0; tt < 8; ++tt) {
            float4 x4 = *(const float4*)(rp[tt] + k);
            acc0[tt] += a4.x * x4.x + a4.y * x4.y + a4.z * x4.z + a4.w * x4.w;
            acc1[tt] += b4.x * x4.x + b4.y * x4.y + b4.z * x4.z + b4.w * x4.w;
            acc2[tt] += c4.x * x4.x + c4.y * x4.y + c4.z * x4.z + c4.w * x4.w;
        }
    }
    // fragment store: idx = ((t*8+wv)*6 + (u*3+g))*256 + (b>>2)*64 + (a&15)*4 + (b&3)
    int wv = a >> 5, u = (a >> 4) & 1, nn = a & 15;
    int lpos = (b >> 2) * 64 + nn * 4 + (b & 3);
#pragma unroll
    for (int tt = 0; tt < 8; ++tt) {
        int t = (bt0 & 255) + tt;
        int base = (t * 8 + wv) * 6 * 256 + lpos;
        gout[base + (u * 3 + 0) * 256] = (f16)acc0[tt];
        gout[base + (u * 3 + 1) * 256] = (f16)acc1[tt];
        gout[base + (u * 3 + 2) * 256] = (f16)acc2[tt];
    }
}

// ---- single-row projection (q / k), no bias ----
__global__ __launch_bounds__(256) void k_proj1(const float* __restrict__ in,
                                               const float* __restrict__ W,
                                               float* __restrict__ out) {
    int bt0 = blockIdx.x * 8;
    int a = threadIdx.x;
    float acc[8];
#pragma unroll
    for (int tt = 0; tt < 8; ++tt) acc[tt] = 0.f;
    const float* w0 = W + a * H_;
    for (int k = 0; k < H_; k += 4) {
        float4 w4 = *(const float4*)(w0 + k);
#pragma unroll
        for (int tt = 0; tt < 8; ++tt) {
            float4 x4 = *(const float4*)(in + (bt0 + tt) * H_ + k);
            acc[tt] += w4.x * x4.x + w4.y * x4.y + w4.z * x4.z + w4.w * x4.w;
        }
    }
#pragma unroll
    for (int tt = 0; tt < 8; ++tt) out[(bt0 + tt) * H_ + a] = acc[tt];
}

// ---- MFMA GRU: ONE block, all 16 batches. 512 threads = 8 waves. ----
// Per step: G[16,768] = h[16,256] @ Whh^T via v_mfma_f32_16x16x32_f16.
// Wave wv owns gate columns j in [wv*32, wv*32+32): 6 N-tiles x 8 K-frags
// = 48 B-frags = 192 regs -- held in AGPRs via asm volatile "+a" pin (a
// volatile asm def cannot be rematerialized, unlike the raw loads the
// compiler kept sinking back into the loop in R3-R5; VGPR budget stays
// ~128 and MFMA reads B directly from AGPR). h_prev for this lane's own
// outputs stays in VGPRs (same lane computes (m,j) every step) -- no
// scattered LDS re-reads. D layout (m89): col=lane&15 (unit), row=
// (lane>>4)*4+reg (batch). Gates lane-local: no shuffles.
__global__ __launch_bounds__(512)
void k_gru(const f16x8* __restrict__ Wp,   // prepped weights (k_wprep)
           const f16* __restrict__ gi,     // [T][8wv][6f][256] halves (k_proj3)
           const float* __restrict__ bhh,  // [768]; only n-gate slice used here
           const float* __restrict__ h0,   // [16][256] f32 or null (zeros)
           float* __restrict__ out,        // [16][256][256] f32
           float* __restrict__ hT) {       // [16][256] f32 or null
    __shared__ __align__(16) f16 shh[2][16 * HP];
    const int tid = threadIdx.x, wv = tid >> 6, l = tid & 63;
    const int n = l & 15, kg = l >> 4;

    // B-fragments -> AGPRs, pinned by volatile asm defs
    f16x8 wfr[2][3][8];
#pragma unroll
    for (int u = 0; u < 2; ++u)
#pragma unroll
        for (int g = 0; g < 3; ++g)
#pragma unroll
            for (int kc = 0; kc < 8; ++kc) {
                wfr[u][g][kc] = Wp[((((wv * 2 + u) * 3 + g) << 3) + kc) * 64 + l];
                asm volatile("" : "+a"(wfr[u][g][kc]));
            }

    const float bhn0 = bhh[512 + wv * 32 + n];
    const float bhn1 = bhh[512 + wv * 32 + 16 + n];

    // h_prev for this lane's own outputs: registers (m = kg*4+r, j = wv*32+u*16+n)
    float hj[2][4];
#pragma unroll
    for (int u = 0; u < 2; ++u) {
        const int j = wv * 32 + u * 16 + n;
#pragma unroll
        for (int r = 0; r < 4; ++r) {
            const int m = kg * 4 + r;
            hj[u][r] = h0 ? h0[m * H_ + j] : 0.f;
            shh[0][m * HP + j] = (f16)hj[u][r];
        }
    }
    __syncthreads();

    const f16* gp = gi + wv * 6 * 256 + l * 4;
    f16x4 gc[6];
#pragma unroll
    for (int f = 0; f < 6; ++f) gc[f] = *(const f16x4*)(gp + f * 256);

    for (int t = 0; t < T_; ++t) {
        const int cur = t & 1;
        f32x4 acc[2][3];
#pragma unroll
        for (int u = 0; u < 2; ++u)
#pragma unroll
            for (int g = 0; g < 3; ++g) acc[u][g] = (f32x4){0.f, 0.f, 0.f, 0.f};

        // A-frags: lane reads h[batch = l&15][k = kc*32 + (l>>4)*8 .. +8]
        const f16* hb = &shh[cur][n * HP + kg * 8];
#pragma unroll
        for (int kc = 0; kc < 8; ++kc) {
            f16x8 af = *(const f16x8*)(hb + kc * 32);
#pragma unroll
            for (int u = 0; u < 2; ++u)
#pragma unroll
                for (int g = 0; g < 3; ++g)
                    asm("v_mfma_f32_16x16x32_f16 %0, %1, %2, %0"
                        : "+v"(acc[u][g])
                        : "v"(af), "a"(wfr[u][g][kc]));
        }

        // gates: lane-local per (batch row m, unit col j)
#pragma unroll
        for (int u = 0; u < 2; ++u) {
            const int j = wv * 32 + u * 16 + n;
            const float bn = u ? bhn1 : bhn0;
#pragma unroll
            for (int r = 0; r < 4; ++r) {
                const int m = kg * 4 + r;
                float hp = hj[u][r];
                float rr = sigmoid_f((float)gc[u * 3 + 0][r] + acc[u][0][r]);
                float zz = sigmoid_f((float)gc[u * 3 + 1][r] + acc[u][1][r]);
                float nv = tanh_f((float)gc[u * 3 + 2][r] + rr * (acc[u][2][r] + bn));
                float hn = (1.f - zz) * nv + zz * hp;
                hj[u][r] = hn;
                out[(m * T_ + t) * H_ + j] = hn;
                shh[cur ^ 1][m * HP + j] = (f16)hn;
                if (hT && t == T_ - 1) hT[m * H_ + j] = hn;
            }
        }

        // single-buffered gi reload for t+1: stays in flight across the barrier
        if (t < T_ - 1) {
            const f16* gq = gp + (t + 1) * (8 * 6 * 256);
#pragma unroll
            for (int f = 0; f < 6; ++f) gc[f] = *(const f16x4*)(gq + f * 256);
        }
        // LDS-only barrier: do NOT drain vmcnt (keeps gi loads + out stores in flight)
        asm volatile("s_waitcnt lgkmcnt(0)" ::: "memory");
        __builtin_amdgcn_s_barrier();
    }
}

// ---- transpose k[b][s][a] -> kT[b][a][s] ----
__global__ __launch_bounds__(256) void k_transpose(const float* __restrict__ k_,
                                                   float* __restrict__ kT) {
    __shared__ float tile[64][65];
    int blk = blockIdx.x;
    int b = blk >> 4;
    int ti = (blk >> 2) & 3;
    int tj = blk & 3;
    int lane = threadIdx.x & 63;
    int ty = threadIdx.x >> 6;
    const float* kb = k_ + b * (T_ * H_);
    for (int r = ty; r < 64; r += 4)
        tile[r][lane] = kb[(ti * 64 + r) * H_ + tj * 64 + lane];
    __syncthreads();
    float* kTb = kT + b * (T_ * H_);
    for (int r = ty; r < 64; r += 4)
        kTb[(tj * 64 + r) * T_ + ti * 64 + lane] = tile[lane][r];
}

// ---- logits[b,t,s] = mask ? v . tanh(q[b,t,:]+k[b,s,:]) : -1e9 ----
__global__ __launch_bounds__(256) void k_scores(const float* __restrict__ q,
                                                const float* __restrict__ kT,
                                                const float* __restrict__ v,
                                                const int* __restrict__ pos,
                                                float* __restrict__ out) {
    __shared__ float sq[4][256];
    __shared__ float sv[256];
    int blk = blockIdx.x;
    int b = blk >> 6;
    int t0 = (blk & 63) * 4;
    int s = threadIdx.x;
    sv[s] = v[s];
#pragma unroll
    for (int tt = 0; tt < 4; ++tt)
        sq[tt][s] = q[((b << 8) + t0 + tt) * H_ + s];
    __syncthreads();
    int ps = pos[(b << 8) + s];
    float acc[4] = {0.f, 0.f, 0.f, 0.f};
    const float* kTb = kT + b * (T_ * H_);
    for (int a = 0; a < H_; ++a) {
        float kv = kTb[a * T_ + s];
        float va = sv[a];
#pragma unroll
        for (int tt = 0; tt < 4; ++tt) {
            float th = tanh_f(sq[tt][a] + kv);
            acc[tt] += va * th;
        }
    }
#pragma unroll
    for (int tt = 0; tt < 4; ++tt) {
        int t = t0 + tt;
        out[((b << 8) + t) * T_ + s] = (t <= ps) ? acc[tt] : -1.0e9f;
    }
}

extern "C" void kernel_launch(void* const* d_in, const int* in_sizes, int n_in,
                              void* d_out, int out_size, void* d_ws, size_t ws_size,
                              hipStream_t stream) {
    (void)in_sizes; (void)n_in; (void)out_size; (void)ws_size;
    const float* inputs   = (const float*)d_in[0];
    const int* targets    = (const int*)d_in[1];
    const float* W_enc   = (const float*)d_in[2];
    const float* b_enc   = (const float*)d_in[3];
    const float* enc_Wih = (const float*)d_in[4];
    const float* enc_Whh = (const float*)d_in[5];
    const float* enc_bih = (const float*)d_in[6];
    const float* enc_bhh = (const float*)d_in[7];
    const float* dec_Wih = (const float*)d_in[8];
    const float* dec_Whh = (const float*)d_in[9];
    const float* dec_bih = (const float*)d_in[10];
    const float* dec_bhh = (const float*)d_in[11];
    const float* Wq = (const float*)d_in[12];
    const float* Wk = (const float*)d_in[13];
    const float* v  = (const float*)d_in[14];
    float* out = (float*)d_out;

    float* ws = (float*)d_ws;
    float* enc_in  = ws;                        // 1,048,576 f
    f16*   gi      = (f16*)(ws + 1048576);      // 3,145,728 halves (1,572,864 f) enc then dec
    float* enc_out = ws + 2621440;              // 1,048,576 f
    float* dec_out = ws + 3670016;              // 1,048,576 f
    f16x8* wpe     = (f16x8*)(ws + 4718592);    // 49,152 f16x8 (98,304 f)
    f16x8* wpd     = (f16x8*)(ws + 4816896);    // 98,304 f
    float* hT      = ws + 4915200;              // 4,096 f
    int*   pos     = (int*)(ws + 4919296);      // 4,096 i
    float* q  = enc_in;     // alias: enc_in dead after dec proj3
    float* kk = (float*)gi; // alias: gi dead after dec GRU
    float* kT = enc_out;    // alias: enc_out dead after proj1(Wk)

    k_wprep<<<384, 256, 0, stream>>>(enc_Whh, dec_Whh, wpe, wpd);
    k_pos_init<<<16, 256, 0, stream>>>(pos);
    k_pos_scan<<<16, 256, 0, stream>>>(targets, pos);
    k_encA<<<512, 256, 0, stream>>>(inputs, W_enc, b_enc, enc_in);
    k_proj3<<<512, 256, 0, stream>>>(enc_in, enc_Wih, enc_bih, enc_bhh, nullptr, gi);
    k_gru<<<1, 512, 0, stream>>>(wpe, gi, enc_bhh, nullptr, enc_out, hT);
    k_proj3<<<512, 256, 0, stream>>>(enc_in, dec_Wih, dec_bih, dec_bhh, targets, gi);
    k_gru<<<1, 512, 0, stream>>>(wpd, gi, dec_bhh, hT, dec_out, nullptr);
    k_proj1<<<512, 256, 0, stream>>>(dec_out, Wq, q);
    k_proj1<<<512, 256, 0, stream>>>(enc_out, Wk, kk);
    k_transpose<<<256, 256, 0, stream>>>(kk, kT);
    k_scores<<<1024, 256, 0, stream>>>(q, kT, v, pos, out);
}

// Round 7
// 989.873 us; speedup vs baseline: 1.5229x; 1.5229x over previous
//
#include <hip/hip_runtime.h>
#include <hip/hip_fp16.h>

#define B_ 16
#define T_ 256
#define D_ 128
#define H_ 256
#define HPITCH 320   // LDS h row pitch in bytes (i8 h)

typedef _Float16 f16;
typedef __attribute__((ext_vector_type(8))) _Float16 f16x8;
typedef __attribute__((ext_vector_type(4))) _Float16 f16x4;
typedef __attribute__((ext_vector_type(4))) int i32x4;

__device__ __forceinline__ float fast_rcp(float x) {
#if __has_builtin(__builtin_amdgcn_rcpf)
    return __builtin_amdgcn_rcpf(x);
#else
    return 1.0f / x;
#endif
}
__device__ __forceinline__ float sigmoid_f(float x) {
    return fast_rcp(1.0f + __expf(-x));
}
__device__ __forceinline__ float tanh_f(float x) {
    float e = __expf(2.0f * x);
    return 1.0f - 2.0f * fast_rcp(1.0f + e);
}

// ---- weight prep: Whh f32 [768][256] -> i8 B-fragments + per-row scales ----
// frag cell (wv,g,kc,lane lf) 16B = Whh[col=g*256+wv*16+(lf&15)][k=kc*64+(lf>>4)*16 ..+16]
// quantized q = rint(w*127/rowmax); dequant scale sc[row] = rowmax/(127*127)
__global__ __launch_bounds__(256) void k_wprep8(const float* __restrict__ wa,
                                                const float* __restrict__ wb,
                                                int* __restrict__ w8a, int* __restrict__ w8b,
                                                float* __restrict__ sca, float* __restrict__ scb) {
    int row_id = blockIdx.x * 4 + (threadIdx.x >> 6); // [0,1536)
    int l = threadIdx.x & 63;
    const float* W = row_id < 768 ? wa : wb;
    int* w8 = row_id < 768 ? w8a : w8b;
    float* sc = row_id < 768 ? sca : scb;
    int r = row_id & 767;
    float4 v = *(const float4*)(W + r * 256 + l * 4);
    float m = fmaxf(fmaxf(fabsf(v.x), fabsf(v.y)), fmaxf(fabsf(v.z), fabsf(v.w)));
#pragma unroll
    for (int d = 1; d < 64; d <<= 1) m = fmaxf(m, __shfl_xor(m, d));
    float qs = m > 0.f ? 127.f / m : 0.f;
    if (l == 0) sc[r] = m / (127.f * 127.f);
    int q0 = (int)rintf(v.x * qs) & 255;
    int q1 = (int)rintf(v.y * qs) & 255;
    int q2 = (int)rintf(v.z * qs) & 255;
    int q3 = (int)rintf(v.w * qs) & 255;
    int pk = q0 | (q1 << 8) | (q2 << 16) | (q3 << 24);
    int g = r >> 8, wv = (r >> 4) & 15, nn = r & 15;
    int kc = l >> 4, kg = (l & 15) >> 2, lf = kg * 16 + nn;
    w8[((((wv * 3 + g) * 4 + kc) * 64) + lf) * 4 + (l & 3)] = pk;
}

// ---- mask precompute: pos[b][s] = first t with targets[b,t]==s (else T) ----
__global__ void k_pos_init(int* __restrict__ pos) {
    pos[blockIdx.x * 256 + threadIdx.x] = T_;
}
__global__ void k_pos_scan(const int* __restrict__ tgt, int* __restrict__ pos) {
    int i = blockIdx.x * 256 + threadIdx.x;
    int b = i >> 8, t = i & 255;
    int s = tgt[i] & 255;
    atomicMin(&pos[(b << 8) + s], t);
}

// ---- enc_in = inputs @ W_enc^T + b_enc ----
__global__ __launch_bounds__(256) void k_encA(const float* __restrict__ in,
                                              const float* __restrict__ W,
                                              const float* __restrict__ bias,
                                              float* __restrict__ out) {
    int bt0 = blockIdx.x * 8;
    int a = threadIdx.x;
    float bv = bias[a];
    float acc[8];
#pragma unroll
    for (int tt = 0; tt < 8; ++tt) acc[tt] = bv;
    const float* wr = W + a * D_;
    for (int k = 0; k < D_; k += 4) {
        float4 w4 = *(const float4*)(wr + k);
#pragma unroll
        for (int tt = 0; tt < 8; ++tt) {
            float4 x4 = *(const float4*)(in + (bt0 + tt) * D_ + k);
            acc[tt] += w4.x * x4.x + w4.y * x4.y + w4.z * x4.z + w4.w * x4.w;
        }
    }
#pragma unroll
    for (int tt = 0; tt < 8; ++tt) out[(bt0 + tt) * H_ + a] = acc[tt];
}

// ---- x_proj -> f16, stored in k_gru2's lane-slot layout; bhh folded into r,z ----
// owner lane of (batch m, col a): tid = (a>>4)*64 + (m>>2)*16 + (a&15); sub r = m&3
// giA[t*1024 + tid] slots: [0..3]=r-gate r0..3, [4..7]=z-gate; giB slots [0..3]=n-gate
__global__ __launch_bounds__(256) void k_proj3(const float* __restrict__ in,
                                               const float* __restrict__ W,
                                               const float* __restrict__ bih,
                                               const float* __restrict__ bhh,
                                               const int* __restrict__ tgt,
                                               f16* __restrict__ giA,
                                               f16* __restrict__ giB) {
    int bt0 = blockIdx.x * 8;
    int b = bt0 >> 8;
    int a = threadIdx.x;
    const float* rp[8];
#pragma unroll
    for (int tt = 0; tt < 8; ++tt) {
        int t = (bt0 & 255) + tt;
        int tsrc = t;
        if (tgt) tsrc = tgt[(b << 8) + ((t + 255) & 255)] & 255; // roll(targets,1)
        rp[tt] = in + ((b << 8) + tsrc) * H_;
    }
    float acc0[8], acc1[8], acc2[8];
    float b0 = bih[a] + bhh[a];               // r gate: fold bhh
    float b1 = bih[a + 256] + bhh[a + 256];   // z gate: fold bhh
    float b2 = bih[a + 512];                  // n gate: bhh applied inside GRU
#pragma unroll
    for (int tt = 0; tt < 8; ++tt) { acc0[tt] = b0; acc1[tt] = b1; acc2[tt] = b2; }
    const float* w0 = W + a * H_;
    const float* w1 = W + (a + 256) * H_;
    const float* w2 = W + (a + 512) * H_;
    for (int k = 0; k < H_; k += 4) {
        float4 a4 = *(const float4*)(w0 + k);
        float4 b4 = *(const float4*)(w1 + k);
        float4 c4 = *(const float4*)(w2 + k);
#pragma unroll
        for (int tt = 0; tt < 8; ++tt) {
            float4 x4 = *(const float4*)(rp[tt] + k);
            acc0[tt] += a4.x * x4.x + a4.y * x4.y + a4.z * x4.z + a4.w * x4.w;
            acc1[tt] += b4.x * x4.x + b4.y * x4.y + b4.z * x4.z + b4.w * x4.w;
            acc2[tt] += c4.x * x4.x + c4.y * x4.y + c4.z * x4.z + c4.w * x4.w;
        }
    }
    int tid_owner = (a >> 4) * 64 + (b >> 2) * 16 + (a & 15);
    int r = b & 3;
#pragma unroll
    for (int tt = 0; tt < 8; ++tt) {
        int t = (bt0 & 255) + tt;
        int base = (t * 1024 + tid_owner);
        giA[base * 8 + r]     = (f16)acc0[tt];
        giA[base * 8 + 4 + r] = (f16)acc1[tt];
        giB[base * 4 + r]     = (f16)acc2[tt];
    }
}

// ---- single-row projection (q / k), no bias ----
__global__ __launch_bounds__(256) void k_proj1(const float* __restrict__ in,
                                               const float* __restrict__ W,
                                               float* __restrict__ out) {
    int bt0 = blockIdx.x * 8;
    int a = threadIdx.x;
    float acc[8];
#pragma unroll
    for (int tt = 0; tt < 8; ++tt) acc[tt] = 0.f;
    const float* w0 = W + a * H_;
    for (int k = 0; k < H_; k += 4) {
        float4 w4 = *(const float4*)(w0 + k);
#pragma unroll
        for (int tt = 0; tt < 8; ++tt) {
            float4 x4 = *(const float4*)(in + (bt0 + tt) * H_ + k);
            acc[tt] += w4.x * x4.x + w4.y * x4.y + w4.z * x4.z + w4.w * x4.w;
        }
    }
#pragma unroll
    for (int tt = 0; tt < 8; ++tt) out[(bt0 + tt) * H_ + a] = acc[tt];
}

// ---- fused i8-MFMA GRU: both encoder+decoder, one block, 1024 thr = 16 waves ----
// Per step: G[16,768] = h[16,256] @ Whh^T via mfma_i32_16x16x64_i8 (K=64: 192
// instrs/step = half the bf16 matrix cost). Wave wv owns cols j in
// [wv*16,wv*16+16) x 3 gates: 12 B-frags = 48 VGPRs -> total ~95 regs, under
// the 128 cap a 1024-thr block forces, so no weight sinking (R3-R6 lesson:
// win by sizing, not pinning). h kept as i8 in LDS ping-pong (scale 127; h in
// (-1,1) by convexity); lane's own h values also in f32 regs. D layout (m89):
// col=lane&15, row=(lane>>4)*4+reg -> gates lane-local. One barrier/step
// (LDS-only waitcnt: gi prefetch + out stores stay in flight).
__global__ __launch_bounds__(1024)
void k_gru2(const int* __restrict__ w8e, const int* __restrict__ w8d,
            const float* __restrict__ sce, const float* __restrict__ scd,
            const f16x8* __restrict__ giAe, const f16x4* __restrict__ giBe,
            const f16x8* __restrict__ giAd, const f16x4* __restrict__ giBd,
            const float* __restrict__ bhhe, const float* __restrict__ bhhd,
            float* __restrict__ enc_out, float* __restrict__ dec_out) {
    __shared__ __align__(16) char shh[2][16 * HPITCH];
    const int tid = threadIdx.x;
    const int wv = tid >> 6, l = tid & 63;
    const int nn = l & 15, kgrp = l >> 4;
    const int j = wv * 16 + nn;

    // zero both h buffers
    for (int i = tid; i < 2 * 16 * HPITCH / 4; i += 1024) ((int*)shh)[i] = 0;
    __syncthreads();

    float hj[4] = {0.f, 0.f, 0.f, 0.f};

    for (int ph = 0; ph < 2; ++ph) {
        const int* w8 = ph ? w8d : w8e;
        const float* scp = ph ? scd : sce;
        const float* bhp = ph ? bhhd : bhhe;
        const f16x8* giA = ph ? giAd : giAe;
        const f16x4* giB = ph ? giBd : giBe;
        float* outp = ph ? dec_out : enc_out;

        const i32x4* w8v = (const i32x4*)w8;
        i32x4 wf[3][4];
#pragma unroll
        for (int g = 0; g < 3; ++g)
#pragma unroll
            for (int kc = 0; kc < 4; ++kc)
                wf[g][kc] = w8v[((wv * 3 + g) * 4 + kc) * 64 + l];
        float sc0 = scp[j], sc1 = scp[256 + j], sc2 = scp[512 + j];
        float bn = bhp[512 + j];

        f16x8 gA = giA[tid];
        f16x4 gB = giB[tid];

        for (int t = 0; t < T_; ++t) {
            const int cur = t & 1;
            i32x4 acc0 = {0, 0, 0, 0}, acc1 = {0, 0, 0, 0}, acc2 = {0, 0, 0, 0};
            const char* hb = &shh[cur][nn * HPITCH + kgrp * 16];
#pragma unroll
            for (int kc = 0; kc < 4; ++kc) {
                i32x4 af = *(const i32x4*)(hb + kc * 64);
                acc0 = __builtin_amdgcn_mfma_i32_16x16x64_i8(af, wf[0][kc], acc0, 0, 0, 0);
                acc1 = __builtin_amdgcn_mfma_i32_16x16x64_i8(af, wf[1][kc], acc1, 0, 0, 0);
                acc2 = __builtin_amdgcn_mfma_i32_16x16x64_i8(af, wf[2][kc], acc2, 0, 0, 0);
            }

            // prefetch next step's gi (in flight across epilogue + barrier)
            f16x8 ngA; f16x4 ngB;
            const bool pf = (t < T_ - 1);
            if (pf) {
                ngA = giA[(t + 1) * 1024 + tid];
                ngB = giB[(t + 1) * 1024 + tid];
            }

            char* hw = &shh[cur ^ 1][0];
#pragma unroll
            for (int r = 0; r < 4; ++r) {
                const int m = kgrp * 4 + r;
                float ghr = (float)acc0[r] * sc0;
                float ghz = (float)acc1[r] * sc1;
                float ghn = (float)acc2[r] * sc2;
                float rr = sigmoid_f((float)gA[r] + ghr);
                float zz = sigmoid_f((float)gA[4 + r] + ghz);
                float nv = tanh_f((float)gB[r] + rr * (ghn + bn));
                float hn = (1.f - zz) * nv + zz * hj[r];
                hj[r] = hn;
                outp[(m * T_ + t) * H_ + j] = hn;
                hw[m * HPITCH + j] = (char)(int)rintf(hn * 127.f);
            }
            if (pf) { gA = ngA; gB = ngB; }
            // LDS-only barrier: keep gi loads + out stores in flight
            asm volatile("s_waitcnt lgkmcnt(0)" ::: "memory");
            __builtin_amdgcn_s_barrier();
        }
    }
}

// ---- transpose k[b][s][a] -> kT[b][a][s] ----
__global__ __launch_bounds__(256) void k_transpose(const float* __restrict__ k_,
                                                   float* __restrict__ kT) {
    __shared__ float tile[64][65];
    int blk = blockIdx.x;
    int b = blk >> 4;
    int ti = (blk >> 2) & 3;
    int tj = blk & 3;
    int lane = threadIdx.x & 63;
    int ty = threadIdx.x >> 6;
    const float* kb = k_ + b * (T_ * H_);
    for (int r = ty; r < 64; r += 4)
        tile[r][lane] = kb[(ti * 64 + r) * H_ + tj * 64 + lane];
    __syncthreads();
    float* kTb = kT + b * (T_ * H_);
    for (int r = ty; r < 64; r += 4)
        kTb[(tj * 64 + r) * T_ + ti * 64 + lane] = tile[lane][r];
}

// ---- logits[b,t,s] = mask ? v . tanh(q[b,t,:]+k[b,s,:]) : -1e9 ----
__global__ __launch_bounds__(256) void k_scores(const float* __restrict__ q,
                                                const float* __restrict__ kT,
                                                const float* __restrict__ v,
                                                const int* __restrict__ pos,
                                                float* __restrict__ out) {
    __shared__ float sq[4][256];
    __shared__ float sv[256];
    int blk = blockIdx.x;
    int b = blk >> 6;
    int t0 = (blk & 63) * 4;
    int s = threadIdx.x;
    sv[s] = v[s];
#pragma unroll
    for (int tt = 0; tt < 4; ++tt)
        sq[tt][s] = q[((b << 8) + t0 + tt) * H_ + s];
    __syncthreads();
    int ps = pos[(b << 8) + s];
    float acc[4] = {0.f, 0.f, 0.f, 0.f};
    const float* kTb = kT + b * (T_ * H_);
    for (int a = 0; a < H_; ++a) {
        float kv = kTb[a * T_ + s];
        float va = sv[a];
#pragma unroll
        for (int tt = 0; tt < 4; ++tt) {
            float th = tanh_f(sq[tt][a] + kv);
            acc[tt] += va * th;
        }
    }
#pragma unroll
    for (int tt = 0; tt < 4; ++tt) {
        int t = t0 + tt;
        out[((b << 8) + t) * T_ + s] = (t <= ps) ? acc[tt] : -1.0e9f;
    }
}

extern "C" void kernel_launch(void* const* d_in, const int* in_sizes, int n_in,
                              void* d_out, int out_size, void* d_ws, size_t ws_size,
                              hipStream_t stream) {
    (void)in_sizes; (void)n_in; (void)out_size; (void)ws_size;
    const float* inputs   = (const float*)d_in[0];
    const int* targets    = (const int*)d_in[1];
    const float* W_enc   = (const float*)d_in[2];
    const float* b_enc   = (const float*)d_in[3];
    const float* enc_Wih = (const float*)d_in[4];
    const float* enc_Whh = (const float*)d_in[5];
    const float* enc_bih = (const float*)d_in[6];
    const float* enc_bhh = (const float*)d_in[7];
    const float* dec_Wih = (const float*)d_in[8];
    const float* dec_Whh = (const float*)d_in[9];
    const float* dec_bih = (const float*)d_in[10];
    const float* dec_bhh = (const float*)d_in[11];
    const float* Wq = (const float*)d_in[12];
    const float* Wk = (const float*)d_in[13];
    const float* v  = (const float*)d_in[14];
    float* out = (float*)d_out;

    float* ws = (float*)d_ws;
    float* enc_in  = ws;                     // 1,048,576 f
    f16*   giAe    = (f16*)(ws + 1048576);   // 2,097,152 h (1,048,576 f)
    f16*   giBe    = (f16*)(ws + 2097152);   // 1,048,576 h (524,288 f)
    f16*   giAd    = (f16*)(ws + 2621440);   // 1,048,576 f
    f16*   giBd    = (f16*)(ws + 3670016);   // 524,288 f
    float* enc_out = ws + 4194304;           // 1,048,576 f
    float* dec_out = ws + 5242880;           // 1,048,576 f
    int*   w8e     = (int*)(ws + 6291456);   // 49,152 dw
    int*   w8d     = (int*)(ws + 6340608);   // 49,152 dw
    float* sce     = ws + 6389760;           // 768
    float* scd     = ws + 6390528;           // 768
    int*   pos     = (int*)(ws + 6391296);   // 4,096
    float* q  = enc_in;          // alias: enc_in dead after the two proj3
    float* kk = ws + 1048576;    // alias giAe (dead after gru)
    float* kT = ws + 2621440;    // alias giAd (dead after gru)

    k_wprep8<<<384, 256, 0, stream>>>(enc_Whh, dec_Whh, w8e, w8d, sce, scd);
    k_pos_init<<<16, 256, 0, stream>>>(pos);
    k_pos_scan<<<16, 256, 0, stream>>>(targets, pos);
    k_encA<<<512, 256, 0, stream>>>(inputs, W_enc, b_enc, enc_in);
    k_proj3<<<512, 256, 0, stream>>>(enc_in, enc_Wih, enc_bih, enc_bhh, nullptr, giAe, giBe);
    k_proj3<<<512, 256, 0, stream>>>(enc_in, dec_Wih, dec_bih, dec_bhh, targets, giAd, giBd);
    k_gru2<<<1, 1024, 0, stream>>>(w8e, w8d, sce, scd,
                                   (const f16x8*)giAe, (const f16x4*)giBe,
                                   (const f16x8*)giAd, (const f16x4*)giBd,
                                   enc_bhh, dec_bhh, enc_out, dec_out);
    k_proj1<<<512, 256, 0, stream>>>(dec_out, Wq, q);
    k_proj1<<<512, 256, 0, stream>>>(enc_out, Wk, kk);
    k_transpose<<<256, 256, 0, stream>>>(kk, kT);
    k_scores<<<1024, 256, 0, stream>>>(q, kT, v, pos, out);
}

// Round 8
// 768.006 us; speedup vs baseline: 1.9628x; 1.2889x over previous
//
#include <hip/hip_runtime.h>
#include <hip/hip_fp16.h>

#define B_ 16
#define T_ 256
#define D_ 128
#define H_ 256

typedef _Float16 f16;
typedef __attribute__((ext_vector_type(2))) _Float16 f16x2;
typedef __attribute__((ext_vector_type(4))) int i32x4;

__device__ __forceinline__ float fast_rcp(float x) {
#if __has_builtin(__builtin_amdgcn_rcpf)
    return __builtin_amdgcn_rcpf(x);
#else
    return 1.0f / x;
#endif
}
__device__ __forceinline__ float sigmoid_f(float x) {
    return fast_rcp(1.0f + __expf(-x));
}
__device__ __forceinline__ float tanh_f(float x) {
    float e = __expf(2.0f * x);
    return 1.0f - 2.0f * fast_rcp(1.0f + e);
}
__device__ __forceinline__ int dot4(int a, int b, int c) {
#if __has_builtin(__builtin_amdgcn_sdot4)
    return __builtin_amdgcn_sdot4(a, b, c, false);
#else
    int d;
    asm("v_dot4_i32_i8 %0, %1, %2, %3" : "=v"(d) : "v"(a), "v"(b), "v"(c));
    return d;
#endif
}

// ---- weight prep: Whh f32 [768][256] -> i8 row-major [768][64 dwords] + row scales ----
// w8[r*64 + l] = bytes k=4l..4l+3 of rint(Whh[r][k] * 127/rowmax); sc[r]=rowmax/127^2
__global__ __launch_bounds__(256) void k_wprep8(const float* __restrict__ wa,
                                                const float* __restrict__ wb,
                                                int* __restrict__ w8a, int* __restrict__ w8b,
                                                float* __restrict__ sca, float* __restrict__ scb) {
    int row_id = blockIdx.x * 4 + (threadIdx.x >> 6); // [0,1536)
    int l = threadIdx.x & 63;
    const float* W = row_id < 768 ? wa : wb;
    int* w8 = row_id < 768 ? w8a : w8b;
    float* sc = row_id < 768 ? sca : scb;
    int r = row_id & 767;
    float4 v = *(const float4*)(W + r * 256 + l * 4);
    float m = fmaxf(fmaxf(fabsf(v.x), fabsf(v.y)), fmaxf(fabsf(v.z), fabsf(v.w)));
#pragma unroll
    for (int d = 1; d < 64; d <<= 1) m = fmaxf(m, __shfl_xor(m, d));
    float qs = m > 0.f ? 127.f / m : 0.f;
    if (l == 0) sc[r] = m / (127.f * 127.f);
    int q0 = (int)rintf(v.x * qs) & 255;
    int q1 = (int)rintf(v.y * qs) & 255;
    int q2 = (int)rintf(v.z * qs) & 255;
    int q3 = (int)rintf(v.w * qs) & 255;
    w8[r * 64 + l] = q0 | (q1 << 8) | (q2 << 16) | (q3 << 24);
}

// ---- mask precompute: pos[b][s] = first t with targets[b,t]==s (else T) ----
__global__ void k_pos_init(int* __restrict__ pos) {
    pos[blockIdx.x * 256 + threadIdx.x] = T_;
}
__global__ void k_pos_scan(const int* __restrict__ tgt, int* __restrict__ pos) {
    int i = blockIdx.x * 256 + threadIdx.x;
    int b = i >> 8, t = i & 255;
    int s = tgt[i] & 255;
    atomicMin(&pos[(b << 8) + s], t);
}

// ---- enc_in = inputs @ W_enc^T + b_enc ----
__global__ __launch_bounds__(256) void k_encA(const float* __restrict__ in,
                                              const float* __restrict__ W,
                                              const float* __restrict__ bias,
                                              float* __restrict__ out) {
    int bt0 = blockIdx.x * 8;
    int a = threadIdx.x;
    float bv = bias[a];
    float acc[8];
#pragma unroll
    for (int tt = 0; tt < 8; ++tt) acc[tt] = bv;
    const float* wr = W + a * D_;
    for (int k = 0; k < D_; k += 4) {
        float4 w4 = *(const float4*)(wr + k);
#pragma unroll
        for (int tt = 0; tt < 8; ++tt) {
            float4 x4 = *(const float4*)(in + (bt0 + tt) * D_ + k);
            acc[tt] += w4.x * x4.x + w4.y * x4.y + w4.z * x4.z + w4.w * x4.w;
        }
    }
#pragma unroll
    for (int tt = 0; tt < 8; ++tt) out[(bt0 + tt) * H_ + a] = acc[tt];
}

// ---- x_proj: giA[(bt)*256+j] = f16x2{gi_r+bih_r+bhh_r, gi_z+bih_z+bhh_z};
//      giB = f16{gi_n+bih_n}; optional teacher-forcing row gather ----
__global__ __launch_bounds__(256) void k_proj3(const float* __restrict__ in,
                                               const float* __restrict__ W,
                                               const float* __restrict__ bih,
                                               const float* __restrict__ bhh,
                                               const int* __restrict__ tgt,
                                               f16x2* __restrict__ giA,
                                               f16* __restrict__ giB) {
    int bt0 = blockIdx.x * 8;
    int b = bt0 >> 8;
    int a = threadIdx.x;
    const float* rp[8];
#pragma unroll
    for (int tt = 0; tt < 8; ++tt) {
        int t = (bt0 & 255) + tt;
        int tsrc = t;
        if (tgt) tsrc = tgt[(b << 8) + ((t + 255) & 255)] & 255; // roll(targets,1)
        rp[tt] = in + ((b << 8) + tsrc) * H_;
    }
    float acc0[8], acc1[8], acc2[8];
    float b0 = bih[a] + bhh[a];
    float b1 = bih[a + 256] + bhh[a + 256];
    float b2 = bih[a + 512];
#pragma unroll
    for (int tt = 0; tt < 8; ++tt) { acc0[tt] = b0; acc1[tt] = b1; acc2[tt] = b2; }
    const float* w0 = W + a * H_;
    const float* w1 = W + (a + 256) * H_;
    const float* w2 = W + (a + 512) * H_;
    for (int k = 0; k < H_; k += 4) {
        float4 a4 = *(const float4*)(w0 + k);
        float4 b4 = *(const float4*)(w1 + k);
        float4 c4 = *(const float4*)(w2 + k);
#pragma unroll
        for (int tt = 0; tt < 8; ++tt) {
            float4 x4 = *(const float4*)(rp[tt] + k);
            acc0[tt] += a4.x * x4.x + a4.y * x4.y + a4.z * x4.z + a4.w * x4.w;
            acc1[tt] += b4.x * x4.x + b4.y * x4.y + b4.z * x4.z + b4.w * x4.w;
            acc2[tt] += c4.x * x4.x + c4.y * x4.y + c4.z * x4.z + c4.w * x4.w;
        }
    }
#pragma unroll
    for (int tt = 0; tt < 8; ++tt) {
        int row = bt0 + tt;
        giA[row * 256 + a] = (f16x2){(f16)acc0[tt], (f16)acc1[tt]};
        giB[row * 256 + a] = (f16)acc2[tt];
    }
}

// ---- single-row projection (q / k), no bias ----
__global__ __launch_bounds__(256) void k_proj1(const float* __restrict__ in,
                                               const float* __restrict__ W,
                                               float* __restrict__ out) {
    int bt0 = blockIdx.x * 8;
    int a = threadIdx.x;
    float acc[8];
#pragma unroll
    for (int tt = 0; tt < 8; ++tt) acc[tt] = 0.f;
    const float* w0 = W + a * H_;
    for (int k = 0; k < H_; k += 4) {
        float4 w4 = *(const float4*)(w0 + k);
#pragma unroll
        for (int tt = 0; tt < 8; ++tt) {
            float4 x4 = *(const float4*)(in + (bt0 + tt) * H_ + k);
            acc[tt] += w4.x * x4.x + w4.y * x4.y + w4.z * x4.z + w4.w * x4.w;
        }
    }
#pragma unroll
    for (int tt = 0; tt < 8; ++tt) out[(bt0 + tt) * H_ + a] = acc[tt];
}

// ---- fused GRU (enc then dec), 16 blocks x 768 threads: one CU per batch ----
// Thread tid = gate row r (g=tid>>8, j=tid&255), FULL K=256 in-thread via 64
// v_dot4_i32_i8 (4 MAC/lane/instr; dot floor 384 cyc/step/CU) -> no cross-lane
// reduce. Weights: 64 dwords i8 loaded by asm-volatile global_load_dwordx4 --
// un-rematerializable, un-sinkable (the R3-R7 killer), ~100 VGPR total.
// h as i8[256] in LDS: dot reads are same-address broadcasts (conflict-free).
// Gate phase: tid<256 (1 of 3 waves/SIMD). 2 barriers/step.
__global__ __launch_bounds__(768)
__attribute__((amdgpu_waves_per_eu(3, 3)))
void k_gru2(const int* __restrict__ w8e, const int* __restrict__ w8d,
            const float* __restrict__ sce, const float* __restrict__ scd,
            const f16x2* __restrict__ giAe, const f16* __restrict__ giBe,
            const f16x2* __restrict__ giAd, const f16* __restrict__ giBd,
            const float* __restrict__ bhhe, const float* __restrict__ bhhd,
            float* __restrict__ enc_out, float* __restrict__ dec_out) {
    __shared__ __align__(16) int sh_h[64];   // h i8 packed, 256 B
    __shared__ float sh_gh[768];
    const int tid = threadIdx.x;
    const int m = blockIdx.x;                // batch
    const int j = tid & 255;                 // unit (column)

    if (tid < 64) sh_h[tid] = 0;
    float hj = 0.f;                          // gate threads' h_prev (exact f32)
    __syncthreads();

    for (int ph = 0; ph < 2; ++ph) {
        const int* w8 = ph ? w8d : w8e;
        const float sc = (ph ? scd : sce)[tid];
        const float bn = (ph ? bhhd : bhhe)[512 + j];
        const f16x2* gA = (ph ? giAd : giAe) + m * (T_ * 256);
        const f16* gB = (ph ? giBd : giBe) + m * (T_ * 256);
        float* outp = (ph ? dec_out : enc_out) + m * (T_ * H_);

        // weights: volatile asm loads -> guaranteed register-resident
        i32x4 wq[16];
        {
            unsigned long long base = (unsigned long long)(w8 + tid * 64);
#pragma unroll
            for (int i = 0; i < 16; ++i)
                asm volatile("global_load_dwordx4 %0, %1, off offset:%2"
                             : "=v"(wq[i]) : "v"(base), "i"(i * 16));
            asm volatile("s_waitcnt vmcnt(0)" ::: "memory");
        }

        for (int t = 0; t < T_; ++t) {
            // gi load issued before dots; in flight during the dot phase
            f16x2 gab = {0, 0};
            f16 gn = 0;
            if (tid < 256) {
                gab = gA[t * 256 + j];
                gn = gB[t * 256 + j];
            }

            int a0 = 0, a1 = 0, a2 = 0, a3 = 0;
            const i32x4* hb = (const i32x4*)sh_h;
#pragma unroll
            for (int i = 0; i < 16; ++i) {
                i32x4 h4 = hb[i];
                a0 = dot4(wq[i][0], h4[0], a0);
                a1 = dot4(wq[i][1], h4[1], a1);
                a2 = dot4(wq[i][2], h4[2], a2);
                a3 = dot4(wq[i][3], h4[3], a3);
            }
            sh_gh[tid] = (float)((a0 + a1) + (a2 + a3)) * sc;
            __syncthreads();

            if (tid < 256) {
                float ghr = sh_gh[j], ghz = sh_gh[256 + j], ghn = sh_gh[512 + j];
                float rr = sigmoid_f((float)gab[0] + ghr);
                float zz = sigmoid_f((float)gab[1] + ghz);
                float nv = tanh_f((float)gn + rr * (ghn + bn));
                float hn = (1.f - zz) * nv + zz * hj;
                hj = hn;
                outp[t * H_ + j] = hn;
                ((char*)sh_h)[j] = (char)(int)rintf(hn * 127.f);
            }
            __syncthreads();
        }
    }
}

// ---- transpose k[b][s][a] -> kT[b][a][s] ----
__global__ __launch_bounds__(256) void k_transpose(const float* __restrict__ k_,
                                                   float* __restrict__ kT) {
    __shared__ float tile[64][65];
    int blk = blockIdx.x;
    int b = blk >> 4;
    int ti = (blk >> 2) & 3;
    int tj = blk & 3;
    int lane = threadIdx.x & 63;
    int ty = threadIdx.x >> 6;
    const float* kb = k_ + b * (T_ * H_);
    for (int r = ty; r < 64; r += 4)
        tile[r][lane] = kb[(ti * 64 + r) * H_ + tj * 64 + lane];
    __syncthreads();
    float* kTb = kT + b * (T_ * H_);
    for (int r = ty; r < 64; r += 4)
        kTb[(tj * 64 + r) * T_ + ti * 64 + lane] = tile[lane][r];
}

// ---- logits[b,t,s] = mask ? v . tanh(q[b,t,:]+k[b,s,:]) : -1e9 ----
__global__ __launch_bounds__(256) void k_scores(const float* __restrict__ q,
                                                const float* __restrict__ kT,
                                                const float* __restrict__ v,
                                                const int* __restrict__ pos,
                                                float* __restrict__ out) {
    __shared__ float sq[4][256];
    __shared__ float sv[256];
    int blk = blockIdx.x;
    int b = blk >> 6;
    int t0 = (blk & 63) * 4;
    int s = threadIdx.x;
    sv[s] = v[s];
#pragma unroll
    for (int tt = 0; tt < 4; ++tt)
        sq[tt][s] = q[((b << 8) + t0 + tt) * H_ + s];
    __syncthreads();
    int ps = pos[(b << 8) + s];
    float acc[4] = {0.f, 0.f, 0.f, 0.f};
    const float* kTb = kT + b * (T_ * H_);
    for (int a = 0; a < H_; ++a) {
        float kv = kTb[a * T_ + s];
        float va = sv[a];
#pragma unroll
        for (int tt = 0; tt < 4; ++tt) {
            float th = tanh_f(sq[tt][a] + kv);
            acc[tt] += va * th;
        }
    }
#pragma unroll
    for (int tt = 0; tt < 4; ++tt) {
        int t = t0 + tt;
        out[((b << 8) + t) * T_ + s] = (t <= ps) ? acc[tt] : -1.0e9f;
    }
}

extern "C" void kernel_launch(void* const* d_in, const int* in_sizes, int n_in,
                              void* d_out, int out_size, void* d_ws, size_t ws_size,
                              hipStream_t stream) {
    (void)in_sizes; (void)n_in; (void)out_size; (void)ws_size;
    const float* inputs   = (const float*)d_in[0];
    const int* targets    = (const int*)d_in[1];
    const float* W_enc   = (const float*)d_in[2];
    const float* b_enc   = (const float*)d_in[3];
    const float* enc_Wih = (const float*)d_in[4];
    const float* enc_Whh = (const float*)d_in[5];
    const float* enc_bih = (const float*)d_in[6];
    const float* enc_bhh = (const float*)d_in[7];
    const float* dec_Wih = (const float*)d_in[8];
    const float* dec_Whh = (const float*)d_in[9];
    const float* dec_bih = (const float*)d_in[10];
    const float* dec_bhh = (const float*)d_in[11];
    const float* Wq = (const float*)d_in[12];
    const float* Wk = (const float*)d_in[13];
    const float* v  = (const float*)d_in[14];
    float* out = (float*)d_out;

    float* ws = (float*)d_ws;
    float* enc_in   = ws;                        // 1,048,576 f
    f16x2* giAe     = (f16x2*)(ws + 1048576);    // 1,048,576 units (4B) = 1,048,576 f
    f16*   giBe     = (f16*)(ws + 2097152);      // 1,048,576 halves = 524,288 f
    f16x2* giAd     = (f16x2*)(ws + 2621440);    // 1,048,576 f
    f16*   giBd     = (f16*)(ws + 3670016);      // 524,288 f
    float* enc_out  = ws + 4194304;              // 1,048,576 f
    float* dec_out  = ws + 5242880;              // 1,048,576 f
    int*   w8e      = (int*)(ws + 6291456);      // 49,152 dw
    int*   w8d      = (int*)(ws + 6340608);      // 49,152 dw
    float* sce      = ws + 6389760;              // 768
    float* scd      = ws + 6390528;              // 768
    int*   pos      = (int*)(ws + 6391296);      // 4,096
    float* q  = enc_in;           // alias: enc_in dead after the two proj3
    float* kk = (float*)giAe;     // alias: gi dead after gru
    float* kT = (float*)giAd;     // alias

    k_wprep8<<<384, 256, 0, stream>>>(enc_Whh, dec_Whh, w8e, w8d, sce, scd);
    k_pos_init<<<16, 256, 0, stream>>>(pos);
    k_pos_scan<<<16, 256, 0, stream>>>(targets, pos);
    k_encA<<<512, 256, 0, stream>>>(inputs, W_enc, b_enc, enc_in);
    k_proj3<<<512, 256, 0, stream>>>(enc_in, enc_Wih, enc_bih, enc_bhh, nullptr, giAe, giBe);
    k_proj3<<<512, 256, 0, stream>>>(enc_in, dec_Wih, dec_bih, dec_bhh, targets, giAd, giBd);
    k_gru2<<<16, 768, 0, stream>>>(w8e, w8d, sce, scd, giAe, giBe, giAd, giBd,
                                   enc_bhh, dec_bhh, enc_out, dec_out);
    k_proj1<<<512, 256, 0, stream>>>(dec_out, Wq, q);
    k_proj1<<<512, 256, 0, stream>>>(enc_out, Wk, kk);
    k_transpose<<<256, 256, 0, stream>>>(kk, kT);
    k_scores<<<1024, 256, 0, stream>>>(q, kT, v, pos, out);
}